// Round 12
// baseline (266.370 us; speedup 1.0000x reference)
//
#include <hip/hip_runtime.h>

#define NNODES 65536
#define FIN 1024
#define NEDGES 2097152
#define NB 64
#define G 256                 // buckets = dst>>8
#define CH (NEDGES / G)       // 8192 edges per scatter block
#define CAPR 96               // slots per (bucket, block) cell in tmp (mean 32, 11 sigma)
#define CAPB 9216             // slots per bucket in csr (mean 8192, ~11 sigma)
#define SCAP 10240            // LDS staging capacity in sort (80 KB)

// ================= kernel A: fused  h1 = x@W1 (unscaled)  ∪  padded-cell scatter ============
// blocks 0-255: gemm, 256 rows each (R10 verified body).
// blocks 256-511: scatter 8192 edges -> LDS partition by bucket -> contiguous run per
//   (bucket,blk) cell at tmp[(bucket*256+blk)*CAPR]. No inter-block dependencies.
union SMemA {
  struct { float sx[2 * 256 * 20]; float sw[2 * 16 * 16]; } g;                       // 42 KB
  struct { int2 ent[CH]; int hist[256], excl[256], cursor[256], sh[256]; } s;        // 68 KB
};

__global__ __launch_bounds__(512) void kmainA(const float* __restrict__ x, const float* __restrict__ W1,
                                              float* __restrict__ h1, const int* __restrict__ src,
                                              const int* __restrict__ dst, const float* __restrict__ ew,
                                              int2* __restrict__ tmp, int* __restrict__ counts) {
  __shared__ SMemA sm;
  const int t = threadIdx.x;
  if (blockIdx.x < 256) {
    // ---------------- GEMM: 256 rows, 64 rg x 4 jg x 2 ks ----------------
    const int jg = t & 3, ks = (t >> 2) & 1, rg = t >> 3;
    const int row0 = blockIdx.x * 256;
    float4 acc4[4];
#pragma unroll
    for (int ri = 0; ri < 4; ++ri) acc4[ri] = make_float4(0.f, 0.f, 0.f, 0.f);
    for (int ch = 0; ch < 32; ++ch) {
#pragma unroll
      for (int i = 0; i < 4; ++i) {       // stage x: 2048 float4, coalesced
        const int v = t + i * 512;
        const int reg = v >> 10, idx = v & 1023;
        const int rr = idx >> 2, k4 = idx & 3;
        const float4 xv =
            *(const float4*)(x + (size_t)(row0 + rr) * FIN + (reg * 32 + ch) * 16 + k4 * 4);
        *(float4*)&sm.g.sx[reg * 5120 + rr * 20 + k4 * 4] = xv;
      }
      if (t < 128) {                      // stage W: 2 regions x 16 k x 16 cols
        const int reg = t >> 6, idx = t & 63;
        const int kk = idx >> 2, c4 = idx & 3;
        *(float4*)&sm.g.sw[reg * 256 + kk * 16 + c4 * 4] =
            *(const float4*)(W1 + (size_t)((reg * 32 + ch) * 16 + kk) * 16 + c4 * 4);
      }
      __syncthreads();
      const int xb = ks * 5120 + rg * 20;
      const int wb = ks * 256 + jg * 4;
#pragma unroll
      for (int k4 = 0; k4 < 4; ++k4) {
        float4 w4[4];
#pragma unroll
        for (int kq = 0; kq < 4; ++kq) w4[kq] = *(const float4*)&sm.g.sw[wb + (k4 * 4 + kq) * 16];
#pragma unroll
        for (int ri = 0; ri < 4; ++ri) {
          const float4 x4 = *(const float4*)&sm.g.sx[xb + ri * 1280 + k4 * 4];
          acc4[ri].x = fmaf(x4.x, w4[0].x, fmaf(x4.y, w4[1].x, fmaf(x4.z, w4[2].x, fmaf(x4.w, w4[3].x, acc4[ri].x))));
          acc4[ri].y = fmaf(x4.x, w4[0].y, fmaf(x4.y, w4[1].y, fmaf(x4.z, w4[2].y, fmaf(x4.w, w4[3].y, acc4[ri].y))));
          acc4[ri].z = fmaf(x4.x, w4[0].z, fmaf(x4.y, w4[1].z, fmaf(x4.z, w4[2].z, fmaf(x4.w, w4[3].z, acc4[ri].z))));
          acc4[ri].w = fmaf(x4.x, w4[0].w, fmaf(x4.y, w4[1].w, fmaf(x4.z, w4[2].w, fmaf(x4.w, w4[3].w, acc4[ri].w))));
        }
      }
      __syncthreads();
    }
    // ks-pair reduction via LDS, then write h1 (unscaled)
    if (ks == 1) {
      float* slot = &sm.g.sx[(rg * 4 + jg) * 16];
#pragma unroll
      for (int ri = 0; ri < 4; ++ri) *(float4*)(slot + ri * 4) = acc4[ri];
    }
    __syncthreads();
    if (ks == 0) {
      const float* slot = &sm.g.sx[(rg * 4 + jg) * 16];
#pragma unroll
      for (int ri = 0; ri < 4; ++ri) {
        const float4 o = *(const float4*)(slot + ri * 4);
        float4 s = acc4[ri];
        s.x += o.x; s.y += o.y; s.z += o.z; s.w += o.w;
        *(float4*)(h1 + (size_t)(row0 + rg + ri * 64) * 16 + jg * 4) = s;
      }
    }
  } else {
    // ---------------- scatter: LDS partition -> padded cells ----------------
    const int blk = blockIdx.x - 256;
    if (t < 256) sm.s.hist[t] = 0;
    __syncthreads();
    int sa[16], da[16]; float wa[16];
    const int base = blk * CH;
#pragma unroll
    for (int i = 0; i < 16; ++i) {
      const int e = base + t + i * 512;
      sa[i] = src[e]; da[i] = dst[e]; wa[i] = ew[e];
      atomicAdd(&sm.s.hist[((unsigned)da[i]) >> 8], 1);
    }
    __syncthreads();
    if (t < 256) sm.s.sh[t] = sm.s.hist[t];
    __syncthreads();
#pragma unroll
    for (int off = 1; off < 256; off <<= 1) {
      int a = (t < 256 && t >= off) ? sm.s.sh[t - off] : 0;
      __syncthreads();
      if (t < 256) sm.s.sh[t] += a;
      __syncthreads();
    }
    if (t < 256) {
      const int e = sm.s.sh[t] - sm.s.hist[t];
      sm.s.excl[t] = e;
      sm.s.cursor[t] = e;
      counts[t * 256 + blk] = sm.s.hist[t];       // cell = bucket*256 + blk
    }
    __syncthreads();
#pragma unroll
    for (int i = 0; i < 16; ++i) {
      const int b = ((unsigned)da[i]) >> 8;
      const int pos = atomicAdd(&sm.s.cursor[b], 1);
      sm.s.ent[pos] = make_int2((sa[i] & 0xFFFF) | ((da[i] & 255) << 16) | (b << 24),
                                __float_as_int(wa[i]));
    }
    __syncthreads();
#pragma unroll
    for (int i = 0; i < 16; ++i) {
      const int idx = t + i * 512;
      const int2 p = sm.s.ent[idx];
      const int b = ((unsigned)p.x) >> 24;
      const int local = idx - sm.s.excl[b];
      if (local < CAPR)
        tmp[(size_t)(b * 256 + blk) * CAPR + local] = make_int2(p.x & 0x00FFFFFF, p.y);
    }
  }
}

// ================= kernel B: per-bucket fine sort + dinv + h1 prescale ============
__global__ __launch_bounds__(512) void ksortE(const int2* __restrict__ tmp, const int* __restrict__ counts,
                                              int2* __restrict__ csr, int* __restrict__ rs,
                                              int* __restrict__ cnt, float* __restrict__ dinv,
                                              float* __restrict__ h1) {
  __shared__ int2 stg[SCAP];                // 80 KB
  __shared__ int hist[256], excl[256], cursor[256];
  __shared__ float degacc[256], dloc[256];
  const int t = threadIdx.x, b = blockIdx.x;
  if (t < 256) { hist[t] = 0; degacc[t] = 0.f; }
  __syncthreads();
  const int seg = t >> 1, half = t & 1;     // 2 threads per cell
  const int len = counts[b * 256 + seg];
  const size_t cellbase = (size_t)(b * 256 + seg) * CAPR;
  // pass 1: histogram + weighted degree
  for (int i = half; i < len; i += 2) {
    const int2 p = tmp[cellbase + i];
    const int fine = (p.x >> 16) & 255;
    atomicAdd(&hist[fine], 1);
    atomicAdd(&degacc[fine], __int_as_float(p.y));
  }
  __syncthreads();
  if (t < 256) excl[t] = hist[t];
  __syncthreads();
#pragma unroll
  for (int off = 1; off < 256; off <<= 1) {
    int a = (t < 256 && t >= off) ? excl[t - off] : 0;
    __syncthreads();
    if (t < 256) excl[t] += a;              // inclusive scan
    __syncthreads();
  }
  if (t < 256) {
    const int e = excl[t] - hist[t];
    cursor[t] = e;
    rs[b * 256 + t] = b * CAPB + e;
    cnt[b * 256 + t] = hist[t];
    const float dn = rsqrtf(1.0f + degacc[t]);
    dloc[t] = dn;
    dinv[b * 256 + t] = dn;
  }
  __syncthreads();
  // pass 2: re-read (L2-warm), sorted placement into LDS
  for (int i = half; i < len; i += 2) {
    const int2 p = tmp[cellbase + i];
    const int fine = (p.x >> 16) & 255;
    const int pos = atomicAdd(&cursor[fine], 1);
    const int2 rec = make_int2(p.x & 0xFFFF, p.y);
    if (pos < SCAP) stg[pos] = rec;
    else csr[(size_t)b * CAPB + pos] = rec; // statistically unreachable
  }
  __syncthreads();
  const int ntot = excl[255];
  for (int j = t; j < ntot; j += 512) csr[(size_t)b * CAPB + j] = stg[j];   // coalesced
  // prescale this bucket's h1 rows: H1 = h1 * dinv
  for (int v = t; v < 1024; v += 512) {
    const int node = v >> 2, q = v & 3;
    float* hp = h1 + (size_t)(b * 256 + node) * 16 + q * 4;
    float4 h = *(float4*)hp;
    const float dn = dloc[node];
    h.x *= dn; h.y *= dn; h.z *= dn; h.w *= dn;
    *(float4*)hp = h;
  }
}

// ============ gather layer 1: agg(H1) -> relu -> @W2 -> H2 (scaled) ============
__global__ __launch_bounds__(256) void kgather1(const float* __restrict__ H1, const int* __restrict__ rs,
                                                const int* __restrict__ cnt, const int2* __restrict__ csr,
                                                const float* __restrict__ dinv,
                                                const float* __restrict__ W2, const float* __restrict__ b1,
                                                float* __restrict__ H2) {
  __shared__ float sh_t[4][16];
  const int tid = threadIdx.x, wv = tid >> 6, l = tid & 63;
  const int n = blockIdx.x * 4 + wv;
  const int f = l & 15, slot = l >> 4;
  const int beg = rs[n], len = cnt[n];
  float acc = 0.f;
  for (int j = slot; j < len; j += 4) {
    const int2 p = csr[beg + j];
    acc = fmaf(__int_as_float(p.y), H1[(size_t)p.x * 16 + f], acc);
  }
  acc += __shfl_xor(acc, 16, 64);
  acc += __shfl_xor(acc, 32, 64);
  if (slot == 0) {
    const float dn = dinv[n];
    float t = dn * (acc + H1[(size_t)n * 16 + f]) + b1[f];
    sh_t[wv][f] = t > 0.f ? t : 0.f;
  }
  __syncthreads();
  if (tid < 16) {
    const int w2 = tid >> 2, c = tid & 3;
    const int nn = blockIdx.x * 4 + w2;
    float s = 0.f;
#pragma unroll
    for (int ff = 0; ff < 16; ++ff) s = fmaf(sh_t[w2][ff], W2[ff * 4 + c], s);
    H2[(size_t)nn * 4 + c] = s * dinv[nn];
  }
}

// ============ gather layer 2: agg(H2) -> relu -> @W3 -> H3 (scaled) ============
__global__ __launch_bounds__(256) void kgather2(const float* __restrict__ H2, const int* __restrict__ rs,
                                                const int* __restrict__ cnt, const int2* __restrict__ csr,
                                                const float* __restrict__ dinv,
                                                const float* __restrict__ W3, const float* __restrict__ b2,
                                                float* __restrict__ H3) {
  const int tid = threadIdx.x, wv = tid >> 6, l = tid & 63;
  const int n = blockIdx.x * 4 + wv;
  const int f = l & 3, slot = l >> 2;
  const int beg = rs[n], len = cnt[n];
  float acc = 0.f;
  for (int j = slot; j < len; j += 16) {
    const int2 p = csr[beg + j];
    acc = fmaf(__int_as_float(p.y), H2[(size_t)p.x * 4 + f], acc);
  }
#pragma unroll
  for (int off = 4; off < 64; off <<= 1) acc += __shfl_xor(acc, off, 64);
  const float dn = dinv[n];
  float t = dn * (acc + H2[(size_t)n * 4 + f]) + b2[f];
  t = t > 0.f ? t : 0.f;
  float p = t * W3[f];
  p += __shfl_xor(p, 1, 64);
  p += __shfl_xor(p, 2, 64);
  if (l == 0) H3[n] = p * dn;
}

// ============ gather layer 3: agg(H3) -> relu -> flat (+ seed out with bias) ============
__global__ __launch_bounds__(256) void kgather3(const float* __restrict__ H3, const int* __restrict__ rs,
                                                const int* __restrict__ cnt, const int2* __restrict__ csr,
                                                const float* __restrict__ dinv,
                                                const float* __restrict__ b3, float* __restrict__ flat,
                                                const float* __restrict__ bout, float* __restrict__ out) {
  const int tid = threadIdx.x, wv = tid >> 6, l = tid & 63;
  if (blockIdx.x == 0 && tid < NB) out[tid] = bout[tid];
  const int n = blockIdx.x * 4 + wv;
  const int beg = rs[n], len = cnt[n];
  float acc = 0.f;
  for (int j = l; j < len; j += 64) {
    const int2 p = csr[beg + j];
    acc = fmaf(__int_as_float(p.y), H3[p.x], acc);
  }
#pragma unroll
  for (int off = 1; off < 64; off <<= 1) acc += __shfl_xor(acc, off, 64);
  if (l == 0) {
    const float dn = dinv[n];
    float t = dn * (acc + H3[n]) + b3[0];
    flat[n] = t > 0.f ? t : 0.f;
  }
}

// ============ final dense: out[b] += partial dot(flat, W_out[b,:]) ============
__global__ __launch_bounds__(256) void kfinal(const float* __restrict__ flat, const float* __restrict__ Wout,
                                              float* __restrict__ out) {
  const int b = blockIdx.x >> 2, q = blockIdx.x & 3;
  const float4* __restrict__ f4 = (const float4*)(flat) + q * 4096;
  const float4* __restrict__ w4 = (const float4*)(Wout + (size_t)b * NNODES) + q * 4096;
  float s = 0.f;
  for (int i = threadIdx.x; i < 4096; i += 256) {
    const float4 a = f4[i];
    const float4 wv = w4[i];
    s += a.x * wv.x + a.y * wv.y + a.z * wv.z + a.w * wv.w;
  }
#pragma unroll
  for (int off = 32; off; off >>= 1) s += __shfl_down(s, off, 64);
  __shared__ float red[4];
  if ((threadIdx.x & 63) == 0) red[threadIdx.x >> 6] = s;
  __syncthreads();
  if (threadIdx.x == 0) atomicAdd(&out[b], red[0] + red[1] + red[2] + red[3]);
}

extern "C" void kernel_launch(void* const* d_in, const int* in_sizes, int n_in,
                              void* d_out, int out_size, void* d_ws, size_t ws_size,
                              hipStream_t stream) {
  const float* x   = (const float*)d_in[0];
  const int*   A   = (const int*)d_in[1];
  const float* ew  = (const float*)d_in[2];
  const float* W1  = (const float*)d_in[3];
  const float* b1  = (const float*)d_in[4];
  const float* W2  = (const float*)d_in[5];
  const float* b2  = (const float*)d_in[6];
  const float* W3  = (const float*)d_in[7];
  const float* b3  = (const float*)d_in[8];
  const float* Wo  = (const float*)d_in[9];
  const float* bo  = (const float*)d_in[10];
  float* out = (float*)d_out;

  const int* src = A;
  const int* dst = A + NEDGES;

  // ---- workspace layout ----
  char* p = (char*)d_ws;
  float* dinv   = (float*)p; p += sizeof(float) * NNODES;
  int*   rsofs  = (int*)p;   p += sizeof(int) * NNODES;
  int*   cnt    = (int*)p;   p += sizeof(int) * NNODES;
  int*   counts = (int*)p;   p += sizeof(int) * NNODES;
  int2*  tmp    = (int2*)p;  p += sizeof(int2) * (size_t)NNODES * CAPR;   // 50.3 MB padded
  int2*  csr    = (int2*)p;  p += sizeof(int2) * (size_t)G * CAPB;        // 18.9 MB padded
  float* h1     = (float*)p; p += sizeof(float) * (size_t)NNODES * 16;
  float* H2     = (float*)p; p += sizeof(float) * (size_t)NNODES * 4;
  float* H3     = (float*)p; p += sizeof(float) * NNODES;
  float* flat   = (float*)p; p += sizeof(float) * NNODES;

  kmainA<<<512, 512, 0, stream>>>(x, W1, h1, src, dst, ew, tmp, counts);
  ksortE<<<G, 512, 0, stream>>>(tmp, counts, csr, rsofs, cnt, dinv, h1);
  kgather1<<<NNODES / 4, 256, 0, stream>>>(h1, rsofs, cnt, csr, dinv, W2, b1, H2);
  kgather2<<<NNODES / 4, 256, 0, stream>>>(H2, rsofs, cnt, csr, dinv, W3, b2, H3);
  kgather3<<<NNODES / 4, 256, 0, stream>>>(H3, rsofs, cnt, csr, dinv, b3, flat, bo, out);
  kfinal<<<NB * 4, 256, 0, stream>>>(flat, Wo, out);
}

// Round 13
// 248.378 us; speedup vs baseline: 1.0724x; 1.0724x over previous
//
#include <hip/hip_runtime.h>

#define NNODES 65536
#define FIN 1024
#define NEDGES 2097152
#define NB 64
#define G 256                 // buckets = dst>>8
#define CH (NEDGES / G)       // 8192 edges per scatter block
#define CAPR 96               // slots per (bucket, block) cell in tmp
#define CAPB 9216             // slots per bucket in csr
#define SCAP 10240            // LDS staging capacity in sort (80 KB)
#define RS 1288               // x region stride (64*20 + 8)
#define WS 272                // w region stride (16*16 + 16)

// ================= kernel 1: h1 = x @ W1 (unscaled), balanced-pipe form =================
// grid 1024 x 256 thr; block = 64 rows; thread (jg,ks,rg) = 4 rows x 4 cols over k-quarter.
// 4 blocks/CU (25 KB LDS) = 16 waves/CU; x-reads 4-lane broadcast; 0.125 LDS-b128/FMA.
union GSMem {
  struct { float sx[4 * RS]; float sw[4 * WS]; } a;   // 24.9 KB
  float red[256 * 16];                                 // 16 KB (ks-reduction)
};

__global__ __launch_bounds__(256) void kgemmF(const float* __restrict__ x, const float* __restrict__ W1,
                                              float* __restrict__ h1) {
  __shared__ GSMem sm;
  const int t = threadIdx.x;
  const int jg = t & 3, ks = (t >> 2) & 3, rg = t >> 4;
  const int row0 = blockIdx.x * 64;
  float4 acc[4];
#pragma unroll
  for (int ri = 0; ri < 4; ++ri) acc[ri] = make_float4(0.f, 0.f, 0.f, 0.f);

  for (int ch = 0; ch < 16; ++ch) {
    const int c0 = ch * 64;
#pragma unroll
    for (int i = 0; i < 4; ++i) {           // stage x: 64 rows x 64 k, coalesced 256B/16 lanes
      const int v = t + i * 256;
      const int rr = v >> 4, kq = v & 15;
      *(float4*)&sm.a.sx[(kq >> 2) * RS + rr * 20 + (kq & 3) * 4] =
          *(const float4*)(x + (size_t)(row0 + rr) * FIN + c0 + kq * 4);
    }
    {                                       // stage W: 64 k x 16 cols
      const int kr = t >> 2, c4 = t & 3;
      *(float4*)&sm.a.sw[(kr >> 4) * WS + (kr & 15) * 16 + c4 * 4] =
          *(const float4*)(W1 + (size_t)(c0 + kr) * 16 + c4 * 4);
    }
    __syncthreads();
    const int xb = ks * RS + rg * 80;       // rg*4 rows
    const int wb = ks * WS + jg * 4;
#pragma unroll
    for (int k4 = 0; k4 < 4; ++k4) {
      float4 w4[4];
#pragma unroll
      for (int kq = 0; kq < 4; ++kq) w4[kq] = *(const float4*)&sm.a.sw[wb + (k4 * 4 + kq) * 16];
#pragma unroll
      for (int ri = 0; ri < 4; ++ri) {
        const float4 x4 = *(const float4*)&sm.a.sx[xb + ri * 20 + k4 * 4];
        acc[ri].x = fmaf(x4.x, w4[0].x, fmaf(x4.y, w4[1].x, fmaf(x4.z, w4[2].x, fmaf(x4.w, w4[3].x, acc[ri].x))));
        acc[ri].y = fmaf(x4.x, w4[0].y, fmaf(x4.y, w4[1].y, fmaf(x4.z, w4[2].y, fmaf(x4.w, w4[3].y, acc[ri].y))));
        acc[ri].z = fmaf(x4.x, w4[0].z, fmaf(x4.y, w4[1].z, fmaf(x4.z, w4[2].z, fmaf(x4.w, w4[3].z, acc[ri].z))));
        acc[ri].w = fmaf(x4.x, w4[0].w, fmaf(x4.y, w4[1].w, fmaf(x4.z, w4[2].w, fmaf(x4.w, w4[3].w, acc[ri].w))));
      }
    }
    __syncthreads();
  }
  // reduce the 4 k-quarters (ks partners differ in bits 2-3 => t + 4*ks')
#pragma unroll
  for (int ri = 0; ri < 4; ++ri) *(float4*)&sm.red[t * 16 + ri * 4] = acc[ri];
  __syncthreads();
  if (ks == 0) {
#pragma unroll
    for (int ri = 0; ri < 4; ++ri) {
      float4 s = acc[ri];
      const float4 a1 = *(const float4*)&sm.red[(t + 4) * 16 + ri * 4];
      const float4 a2 = *(const float4*)&sm.red[(t + 8) * 16 + ri * 4];
      const float4 a3 = *(const float4*)&sm.red[(t + 12) * 16 + ri * 4];
      s.x += a1.x + a2.x + a3.x;
      s.y += a1.y + a2.y + a3.y;
      s.z += a1.z + a2.z + a3.z;
      s.w += a1.w + a2.w + a3.w;
      *(float4*)(h1 + (size_t)(row0 + rg * 4 + ri) * 16 + jg * 4) = s;
    }
  }
}

// ================= kernel 2: padded-cell scatter (R12 body, standalone) =================
__global__ __launch_bounds__(512) void kscatF(const int* __restrict__ src, const int* __restrict__ dst,
                                              const float* __restrict__ ew, int2* __restrict__ tmp,
                                              int* __restrict__ counts) {
  __shared__ int2 ent[CH];                  // 64 KB
  __shared__ int hist[256], excl[256], cursor[256], sh[256];
  const int t = threadIdx.x, blk = blockIdx.x;
  if (t < 256) hist[t] = 0;
  __syncthreads();
  int sa[16], da[16]; float wa[16];
  const int base = blk * CH;
#pragma unroll
  for (int i = 0; i < 16; ++i) {
    const int e = base + t + i * 512;
    sa[i] = src[e]; da[i] = dst[e]; wa[i] = ew[e];
    atomicAdd(&hist[((unsigned)da[i]) >> 8], 1);
  }
  __syncthreads();
  if (t < 256) sh[t] = hist[t];
  __syncthreads();
#pragma unroll
  for (int off = 1; off < 256; off <<= 1) {
    int a = (t < 256 && t >= off) ? sh[t - off] : 0;
    __syncthreads();
    if (t < 256) sh[t] += a;
    __syncthreads();
  }
  if (t < 256) {
    const int e = sh[t] - hist[t];
    excl[t] = e;
    cursor[t] = e;
    counts[t * 256 + blk] = hist[t];        // cell = bucket*256 + blk
  }
  __syncthreads();
#pragma unroll
  for (int i = 0; i < 16; ++i) {
    const int b = ((unsigned)da[i]) >> 8;
    const int pos = atomicAdd(&cursor[b], 1);
    ent[pos] = make_int2((sa[i] & 0xFFFF) | ((da[i] & 255) << 16) | (b << 24),
                         __float_as_int(wa[i]));
  }
  __syncthreads();
#pragma unroll
  for (int i = 0; i < 16; ++i) {
    const int idx = t + i * 512;
    const int2 p = ent[idx];
    const int b = ((unsigned)p.x) >> 24;
    const int local = idx - excl[b];
    if (local < CAPR)
      tmp[(size_t)(b * 256 + blk) * CAPR + local] = make_int2(p.x & 0x00FFFFFF, p.y);
  }
}

// ================= kernel 3: per-bucket fine sort + dinv + h1 prescale (R12, unchanged) ====
__global__ __launch_bounds__(512) void ksortE(const int2* __restrict__ tmp, const int* __restrict__ counts,
                                              int2* __restrict__ csr, int* __restrict__ rs,
                                              int* __restrict__ cnt, float* __restrict__ dinv,
                                              float* __restrict__ h1) {
  __shared__ int2 stg[SCAP];                // 80 KB
  __shared__ int hist[256], excl[256], cursor[256];
  __shared__ float degacc[256], dloc[256];
  const int t = threadIdx.x, b = blockIdx.x;
  if (t < 256) { hist[t] = 0; degacc[t] = 0.f; }
  __syncthreads();
  const int seg = t >> 1, half = t & 1;
  const int len = counts[b * 256 + seg];
  const size_t cellbase = (size_t)(b * 256 + seg) * CAPR;
  for (int i = half; i < len; i += 2) {
    const int2 p = tmp[cellbase + i];
    const int fine = (p.x >> 16) & 255;
    atomicAdd(&hist[fine], 1);
    atomicAdd(&degacc[fine], __int_as_float(p.y));
  }
  __syncthreads();
  if (t < 256) excl[t] = hist[t];
  __syncthreads();
#pragma unroll
  for (int off = 1; off < 256; off <<= 1) {
    int a = (t < 256 && t >= off) ? excl[t - off] : 0;
    __syncthreads();
    if (t < 256) excl[t] += a;
    __syncthreads();
  }
  if (t < 256) {
    const int e = excl[t] - hist[t];
    cursor[t] = e;
    rs[b * 256 + t] = b * CAPB + e;
    cnt[b * 256 + t] = hist[t];
    const float dn = rsqrtf(1.0f + degacc[t]);
    dloc[t] = dn;
    dinv[b * 256 + t] = dn;
  }
  __syncthreads();
  for (int i = half; i < len; i += 2) {
    const int2 p = tmp[cellbase + i];
    const int fine = (p.x >> 16) & 255;
    const int pos = atomicAdd(&cursor[fine], 1);
    const int2 rec = make_int2(p.x & 0xFFFF, p.y);
    if (pos < SCAP) stg[pos] = rec;
    else csr[(size_t)b * CAPB + pos] = rec;
  }
  __syncthreads();
  const int ntot = excl[255];
  for (int j = t; j < ntot; j += 512) csr[(size_t)b * CAPB + j] = stg[j];
  for (int v = t; v < 1024; v += 512) {
    const int node = v >> 2, q = v & 3;
    float* hp = h1 + (size_t)(b * 256 + node) * 16 + q * 4;
    float4 h = *(float4*)hp;
    const float dn = dloc[node];
    h.x *= dn; h.y *= dn; h.z *= dn; h.w *= dn;
    *(float4*)hp = h;
  }
}

// ============ gather layer 1: agg(H1) -> relu -> @W2 -> H2 (scaled) ============
__global__ __launch_bounds__(256) void kgather1(const float* __restrict__ H1, const int* __restrict__ rs,
                                                const int* __restrict__ cnt, const int2* __restrict__ csr,
                                                const float* __restrict__ dinv,
                                                const float* __restrict__ W2, const float* __restrict__ b1,
                                                float* __restrict__ H2) {
  __shared__ float sh_t[4][16];
  const int tid = threadIdx.x, wv = tid >> 6, l = tid & 63;
  const int n = blockIdx.x * 4 + wv;
  const int f = l & 15, slot = l >> 4;
  const int beg = rs[n], len = cnt[n];
  float acc = 0.f;
  for (int j = slot; j < len; j += 4) {
    const int2 p = csr[beg + j];
    acc = fmaf(__int_as_float(p.y), H1[(size_t)p.x * 16 + f], acc);
  }
  acc += __shfl_xor(acc, 16, 64);
  acc += __shfl_xor(acc, 32, 64);
  if (slot == 0) {
    const float dn = dinv[n];
    float t = dn * (acc + H1[(size_t)n * 16 + f]) + b1[f];
    sh_t[wv][f] = t > 0.f ? t : 0.f;
  }
  __syncthreads();
  if (tid < 16) {
    const int w2 = tid >> 2, c = tid & 3;
    const int nn = blockIdx.x * 4 + w2;
    float s = 0.f;
#pragma unroll
    for (int ff = 0; ff < 16; ++ff) s = fmaf(sh_t[w2][ff], W2[ff * 4 + c], s);
    H2[(size_t)nn * 4 + c] = s * dinv[nn];
  }
}

// ============ gather layer 2: agg(H2) -> relu -> @W3 -> H3 (scaled) ============
__global__ __launch_bounds__(256) void kgather2(const float* __restrict__ H2, const int* __restrict__ rs,
                                                const int* __restrict__ cnt, const int2* __restrict__ csr,
                                                const float* __restrict__ dinv,
                                                const float* __restrict__ W3, const float* __restrict__ b2,
                                                float* __restrict__ H3) {
  const int tid = threadIdx.x, wv = tid >> 6, l = tid & 63;
  const int n = blockIdx.x * 4 + wv;
  const int f = l & 3, slot = l >> 2;
  const int beg = rs[n], len = cnt[n];
  float acc = 0.f;
  for (int j = slot; j < len; j += 16) {
    const int2 p = csr[beg + j];
    acc = fmaf(__int_as_float(p.y), H2[(size_t)p.x * 4 + f], acc);
  }
#pragma unroll
  for (int off = 4; off < 64; off <<= 1) acc += __shfl_xor(acc, off, 64);
  const float dn = dinv[n];
  float t = dn * (acc + H2[(size_t)n * 4 + f]) + b2[f];
  t = t > 0.f ? t : 0.f;
  float p = t * W3[f];
  p += __shfl_xor(p, 1, 64);
  p += __shfl_xor(p, 2, 64);
  if (l == 0) H3[n] = p * dn;
}

// ============ gather layer 3: agg(H3) -> relu -> flat (+ seed out with bias) ============
__global__ __launch_bounds__(256) void kgather3(const float* __restrict__ H3, const int* __restrict__ rs,
                                                const int* __restrict__ cnt, const int2* __restrict__ csr,
                                                const float* __restrict__ dinv,
                                                const float* __restrict__ b3, float* __restrict__ flat,
                                                const float* __restrict__ bout, float* __restrict__ out) {
  const int tid = threadIdx.x, wv = tid >> 6, l = tid & 63;
  if (blockIdx.x == 0 && tid < NB) out[tid] = bout[tid];
  const int n = blockIdx.x * 4 + wv;
  const int beg = rs[n], len = cnt[n];
  float acc = 0.f;
  for (int j = l; j < len; j += 64) {
    const int2 p = csr[beg + j];
    acc = fmaf(__int_as_float(p.y), H3[p.x], acc);
  }
#pragma unroll
  for (int off = 1; off < 64; off <<= 1) acc += __shfl_xor(acc, off, 64);
  if (l == 0) {
    const float dn = dinv[n];
    float t = dn * (acc + H3[n]) + b3[0];
    flat[n] = t > 0.f ? t : 0.f;
  }
}

// ============ final dense: out[b] += partial dot(flat, W_out[b,:]) ============
__global__ __launch_bounds__(256) void kfinal(const float* __restrict__ flat, const float* __restrict__ Wout,
                                              float* __restrict__ out) {
  const int b = blockIdx.x >> 2, q = blockIdx.x & 3;
  const float4* __restrict__ f4 = (const float4*)(flat) + q * 4096;
  const float4* __restrict__ w4 = (const float4*)(Wout + (size_t)b * NNODES) + q * 4096;
  float s = 0.f;
  for (int i = threadIdx.x; i < 4096; i += 256) {
    const float4 a = f4[i];
    const float4 wv = w4[i];
    s += a.x * wv.x + a.y * wv.y + a.z * wv.z + a.w * wv.w;
  }
#pragma unroll
  for (int off = 32; off; off >>= 1) s += __shfl_down(s, off, 64);
  __shared__ float red[4];
  if ((threadIdx.x & 63) == 0) red[threadIdx.x >> 6] = s;
  __syncthreads();
  if (threadIdx.x == 0) atomicAdd(&out[b], red[0] + red[1] + red[2] + red[3]);
}

extern "C" void kernel_launch(void* const* d_in, const int* in_sizes, int n_in,
                              void* d_out, int out_size, void* d_ws, size_t ws_size,
                              hipStream_t stream) {
  const float* x   = (const float*)d_in[0];
  const int*   A   = (const int*)d_in[1];
  const float* ew  = (const float*)d_in[2];
  const float* W1  = (const float*)d_in[3];
  const float* b1  = (const float*)d_in[4];
  const float* W2  = (const float*)d_in[5];
  const float* b2  = (const float*)d_in[6];
  const float* W3  = (const float*)d_in[7];
  const float* b3  = (const float*)d_in[8];
  const float* Wo  = (const float*)d_in[9];
  const float* bo  = (const float*)d_in[10];
  float* out = (float*)d_out;

  const int* src = A;
  const int* dst = A + NEDGES;

  // ---- workspace layout ----
  char* p = (char*)d_ws;
  float* dinv   = (float*)p; p += sizeof(float) * NNODES;
  int*   rsofs  = (int*)p;   p += sizeof(int) * NNODES;
  int*   cnt    = (int*)p;   p += sizeof(int) * NNODES;
  int*   counts = (int*)p;   p += sizeof(int) * NNODES;
  int2*  tmp    = (int2*)p;  p += sizeof(int2) * (size_t)NNODES * CAPR;   // 50.3 MB padded
  int2*  csr    = (int2*)p;  p += sizeof(int2) * (size_t)G * CAPB;        // 18.9 MB padded
  float* h1     = (float*)p; p += sizeof(float) * (size_t)NNODES * 16;
  float* H2     = (float*)p; p += sizeof(float) * (size_t)NNODES * 4;
  float* H3     = (float*)p; p += sizeof(float) * NNODES;
  float* flat   = (float*)p; p += sizeof(float) * NNODES;

  kgemmF<<<NNODES / 64, 256, 0, stream>>>(x, W1, h1);
  kscatF<<<G, 512, 0, stream>>>(src, dst, ew, tmp, counts);
  ksortE<<<G, 512, 0, stream>>>(tmp, counts, csr, rsofs, cnt, dinv, h1);
  kgather1<<<NNODES / 4, 256, 0, stream>>>(h1, rsofs, cnt, csr, dinv, W2, b1, H2);
  kgather2<<<NNODES / 4, 256, 0, stream>>>(H2, rsofs, cnt, csr, dinv, W3, b2, H3);
  kgather3<<<NNODES / 4, 256, 0, stream>>>(H3, rsofs, cnt, csr, dinv, b3, flat, bo, out);
  kfinal<<<NB * 4, 256, 0, stream>>>(flat, Wo, out);
}